// Round 1
// baseline (10.596 us; speedup 1.0000x reference)
//
#include <hip/hip_runtime.h>

// UniGSA_layer: algebraic identity.
//   s = -inf where H==0; softmax mass therefore lies entirely on H==1 entries;
//   coef[n,h] = sum_e H[n,e]*a[n,h,e] = sum of ALL nonzero softmax entries = 1.
//   => rst = fs * 1 = fs  => output == feat, exactly (in exact arithmetic).
// So the kernel is a pure copy of feat (N x NH*NF = 10000 x 256 f32, 10.24 MB).

__global__ void UniGSA_copy_kernel(const float* __restrict__ in,
                                   float* __restrict__ out,
                                   int n4) {
    int i = blockIdx.x * blockDim.x + threadIdx.x;
    if (i < n4) {
        reinterpret_cast<float4*>(out)[i] =
            reinterpret_cast<const float4*>(in)[i];
    }
}

extern "C" void kernel_launch(void* const* d_in, const int* in_sizes, int n_in,
                              void* d_out, int out_size, void* d_ws, size_t ws_size,
                              hipStream_t stream) {
    const float* feat = (const float*)d_in[0];
    float* out = (float*)d_out;

    // out_size = 10000*256 = 2,560,000 floats, divisible by 4.
    int n4 = out_size / 4;
    int block = 256;
    int grid = (n4 + block - 1) / block;
    UniGSA_copy_kernel<<<grid, block, 0, stream>>>(feat, out, n4);

    // Scalar tail (defensive; empty for this shape).
    int tail = out_size - n4 * 4;
    if (tail > 0) {
        // handle with a tiny 1-block launch
        hipMemcpyAsync((char*)d_out + (size_t)n4 * 16,
                       (const char*)feat + (size_t)n4 * 16,
                       (size_t)tail * sizeof(float),
                       hipMemcpyDeviceToDevice, stream);
    }
}